// Round 8
// baseline (128.357 us; speedup 1.0000x reference)
//
#include <hip/hip_runtime.h>

#define Nn 100000
#define Ee 1600000
#define HID 128
#define IN_DIM 5
#define N5 (Nn * IN_DIM)

// ---- bucket geometry: 1024 nodes/bucket, 98 buckets ----
#define SH2 10
#define BSZ2 1024
#define NB2 98
#define BCAP 18432        // expect ~16384, sigma ~127 -> +16 sigma headroom

#define PCHUNK 2000       // edges per partition block
#define PBLK (Ee / PCHUNK)   // 800 blocks

#define CPB1 8            // chunks/bucket for deg pass (512 threads)
#define CPB2 12           // chunks/bucket for gather passes -> chunk <= 1536 records
#define TPB 256           // threads for gather passes
#define MAXK 6            // 1536 / 256: exact per-thread record bound

// ---------- kernel 1: one-pass radix partition of the edge list ----------
// rec = (d_local << 17) | src   (src < 2^17, d_local < 2^10)
__global__ __launch_bounds__(512) void partition_kernel(const int* __restrict__ src,
                                                        const int* __restrict__ dst,
                                                        unsigned int* __restrict__ recs,
                                                        int* __restrict__ bcnt) {
    __shared__ unsigned int stage[PCHUNK];   // 8 KB
    __shared__ int hist[NB2 + 1];
    __shared__ int cur[NB2];
    __shared__ int gbase[NB2];
    int e0 = blockIdx.x * PCHUNK;
    if (threadIdx.x <= NB2) hist[threadIdx.x] = 0;
    __syncthreads();
    for (int e = e0 + threadIdx.x; e < e0 + PCHUNK; e += 512)
        atomicAdd(&hist[(dst[e] >> SH2) + 1], 1);
    __syncthreads();
    if (threadIdx.x == 0)
        for (int b = 1; b <= NB2; ++b) hist[b] += hist[b - 1];
    __syncthreads();
    if (threadIdx.x < NB2) {
        int c0 = hist[threadIdx.x], c1 = hist[threadIdx.x + 1];
        cur[threadIdx.x] = c0;
        gbase[threadIdx.x] = atomicAdd(&bcnt[threadIdx.x], c1 - c0);
    }
    __syncthreads();
    for (int e = e0 + threadIdx.x; e < e0 + PCHUNK; e += 512) {
        int d = dst[e], s = src[e];
        int b = d >> SH2;
        int slot = atomicAdd(&cur[b], 1);
        stage[slot] = ((unsigned int)(d & (BSZ2 - 1)) << 17) | (unsigned int)s;
    }
    __syncthreads();
    int wave = threadIdx.x >> 6, lane = threadIdx.x & 63;
    for (int b = wave; b < NB2; b += 8) {
        int c0 = hist[b], len = hist[b + 1] - c0;
        unsigned int* o = recs + (size_t)b * BCAP + gbase[b];
        for (int i = lane; i < len; i += 64) o[i] = stage[c0 + i];
    }
}

// ---------- kernel 2: per-bucket in-degree from records ----------
__global__ __launch_bounds__(512) void degbin2_kernel(const unsigned int* __restrict__ recs,
                                                      const int* __restrict__ bcnt,
                                                      float* __restrict__ degp) {
    __shared__ int acc[BSZ2];                // 4 KB
    int b = blockIdx.x / CPB1, c = blockIdx.x % CPB1;
    int n = bcnt[b];
    int r0 = (int)((long long)n * c / CPB1), r1 = (int)((long long)n * (c + 1) / CPB1);
    for (int i = threadIdx.x; i < BSZ2; i += 512) acc[i] = 0;
    __syncthreads();
    const unsigned int* R = recs + (size_t)b * BCAP;
    int i = r0 + (int)threadIdx.x;
    for (; i + 3 * 512 < r1; i += 4 * 512) {
        unsigned int ra = R[i], rb = R[i + 512], rc = R[i + 1024], rd = R[i + 1536];
        atomicAdd(&acc[ra >> 17], 1);
        atomicAdd(&acc[rb >> 17], 1);
        atomicAdd(&acc[rc >> 17], 1);
        atomicAdd(&acc[rd >> 17], 1);
    }
    for (; i < r1; i += 512) atomicAdd(&acc[R[i] >> 17], 1);
    __syncthreads();
    int base = b << SH2;
    int cnt = min(BSZ2, Nn - base);
    float* o = degp + (size_t)c * Nn + base;
    for (int j = threadIdx.x; j < cnt; j += 512) o[j] = (float)acc[j];
}

// ---------- kernel 3: dinv = rsqrt(deg+1); xd8 = x*dinv (8-float padded rows) ----------
__global__ void prep_kernel(const float* __restrict__ x, const float* __restrict__ degp,
                            float* __restrict__ dinv, float* __restrict__ xd8) {
    int i = blockIdx.x * blockDim.x + threadIdx.x;
    if (i < Nn) {
        float dg = 1.0f;
        #pragma unroll
        for (int c = 0; c < CPB1; ++c) dg += degp[(size_t)c * Nn + i];
        float di = rsqrtf(dg);
        dinv[i] = di;
        #pragma unroll
        for (int k = 0; k < IN_DIM; ++k)
            xd8[(size_t)i * 8 + k] = x[i * IN_DIM + k] * di;
    }
}

// ---------- kernel 4: layer-1 input aggregation (predicated MAXK pipeline) ----------
__global__ __launch_bounds__(TPB) void pre1bin3_kernel(const unsigned int* __restrict__ recs,
                                                       const int* __restrict__ bcnt,
                                                       const float* __restrict__ xd8,
                                                       float* __restrict__ pre1p) {
    __shared__ float acc[BSZ2 * IN_DIM];     // 20 KB
    int b = blockIdx.x / CPB2, c = blockIdx.x % CPB2;
    int n = bcnt[b];
    int r0 = (int)((long long)n * c / CPB2), r1 = (int)((long long)n * (c + 1) / CPB2);
    float4* accv = (float4*)acc;
    for (int i = threadIdx.x; i < BSZ2 * IN_DIM / 4; i += TPB)
        accv[i] = make_float4(0.f, 0.f, 0.f, 0.f);
    __syncthreads();
    const unsigned int* R = recs + (size_t)b * BCAP;
    int i0 = r0 + (int)threadIdx.x;
    unsigned int rr[MAXK];
    float4 v[MAXK];
    float  w[MAXK];
    // phase 1: all record loads in flight
    #pragma unroll
    for (int q = 0; q < MAXK; ++q)
        if (i0 + q * TPB < r1) rr[q] = R[i0 + q * TPB];
    // phase 2: all gathers in flight (2 loads each, independent)
    #pragma unroll
    for (int q = 0; q < MAXK; ++q)
        if (i0 + q * TPB < r1) {
            int s = (int)(rr[q] & 0x1FFFFu);
            v[q] = *(const float4*)&xd8[(size_t)s * 8];
            w[q] = xd8[(size_t)s * 8 + 4];
        }
    // phase 3: LDS accumulation
    #pragma unroll
    for (int q = 0; q < MAXK; ++q)
        if (i0 + q * TPB < r1) {
            int dl = (int)(rr[q] >> 17) * IN_DIM;
            atomicAdd(&acc[dl + 0], v[q].x);
            atomicAdd(&acc[dl + 1], v[q].y);
            atomicAdd(&acc[dl + 2], v[q].z);
            atomicAdd(&acc[dl + 3], v[q].w);
            atomicAdd(&acc[dl + 4], w[q]);
        }
    __syncthreads();
    int base = b << SH2;
    int cnt4 = min(BSZ2, Nn - base) * IN_DIM / 4;
    float4* o = (float4*)(pre1p + (size_t)c * N5 + (size_t)base * IN_DIM);
    for (int j = threadIdx.x; j < cnt4; j += TPB) o[j] = accv[j];
}

// ---------- kernel 5: fused partial-reduce + layer-1 finish + ReLU + layer-2 proj ----------
__global__ __launch_bounds__(256) void node1_kernel(const float* __restrict__ pre1p,
                             const float* __restrict__ xd8,
                             const float* __restrict__ W1, const float* __restrict__ b1,
                             const float* __restrict__ W2, const float* __restrict__ dinv,
                             float* __restrict__ h2d) {
    __shared__ float w1s[IN_DIM * HID];      // 2.5 KB
    __shared__ float w2s[HID], b1s[HID];
    int tid = threadIdx.x;
    for (int j = tid; j < IN_DIM * HID; j += 256) w1s[j] = W1[j];
    if (tid < HID) { w2s[tid] = W2[tid]; b1s[tid] = b1[tid]; }
    __syncthreads();
    int nnode = blockIdx.x * 256 + tid;
    if (nnode >= Nn) return;
    float a5[IN_DIM] = {0.f, 0.f, 0.f, 0.f, 0.f};
    #pragma unroll
    for (int c = 0; c < CPB2; ++c) {
        const float* p = pre1p + (size_t)c * N5 + (size_t)nnode * IN_DIM;
        #pragma unroll
        for (int k = 0; k < IN_DIM; ++k) a5[k] += p[k];
    }
    float di = dinv[nnode];
    #pragma unroll
    for (int k = 0; k < IN_DIM; ++k)
        a5[k] = (a5[k] + xd8[(size_t)nnode * 8 + k]) * di;  // neighbors + self-loop
    float accp = 0.f;
    #pragma unroll
    for (int f = 0; f < HID; ++f) {
        float v = b1s[f];
        #pragma unroll
        for (int k = 0; k < IN_DIM; ++k) v += a5[k] * w1s[k * HID + f];
        v = fmaxf(v, 0.f);
        accp += v * w2s[f];
    }
    h2d[nnode] = accp * di;
}

// ---------- kernel 6: layer-2 scalar aggregation (predicated MAXK pipeline) ----------
__global__ __launch_bounds__(TPB) void out2bin3_kernel(const unsigned int* __restrict__ recs,
                                                       const int* __restrict__ bcnt,
                                                       const float* __restrict__ h2d,
                                                       float* __restrict__ outp) {
    __shared__ float acc[BSZ2];              // 4 KB
    int b = blockIdx.x / CPB2, c = blockIdx.x % CPB2;
    int n = bcnt[b];
    int r0 = (int)((long long)n * c / CPB2), r1 = (int)((long long)n * (c + 1) / CPB2);
    for (int i = threadIdx.x; i < BSZ2; i += TPB) acc[i] = 0.f;
    __syncthreads();
    const unsigned int* R = recs + (size_t)b * BCAP;
    int i0 = r0 + (int)threadIdx.x;
    unsigned int rr[MAXK];
    float h[MAXK];
    #pragma unroll
    for (int q = 0; q < MAXK; ++q)
        if (i0 + q * TPB < r1) rr[q] = R[i0 + q * TPB];
    #pragma unroll
    for (int q = 0; q < MAXK; ++q)
        if (i0 + q * TPB < r1) h[q] = h2d[rr[q] & 0x1FFFFu];
    #pragma unroll
    for (int q = 0; q < MAXK; ++q)
        if (i0 + q * TPB < r1) atomicAdd(&acc[rr[q] >> 17], h[q]);
    __syncthreads();
    int base = b << SH2;
    int cnt = min(BSZ2, Nn - base);
    float* o = outp + (size_t)c * Nn + base;
    for (int j = threadIdx.x; j < cnt; j += TPB) o[j] = acc[j];
}

// ---------- kernel 7: final reduce + self-loop + b2 ----------
__global__ void final_kernel(const float* __restrict__ outp, const float* __restrict__ h2d,
                             const float* __restrict__ dinv, const float* __restrict__ b2,
                             float* __restrict__ out) {
    int n = blockIdx.x * blockDim.x + threadIdx.x;
    if (n < Nn) {
        float v = 0.f;
        #pragma unroll
        for (int c = 0; c < CPB2; ++c) v += outp[(size_t)c * Nn + n];
        out[n] = (v + h2d[n]) * dinv[n] + b2[0];
    }
}

extern "C" void kernel_launch(void* const* d_in, const int* in_sizes, int n_in,
                              void* d_out, int out_size, void* d_ws, size_t ws_size,
                              hipStream_t stream) {
    const float* x  = (const float*)d_in[0];
    const int*   ei = (const int*)d_in[1];     // [2, E]: src row then dst row
    const float* W1 = (const float*)d_in[2];
    const float* b1 = (const float*)d_in[3];
    const float* W2 = (const float*)d_in[4];
    const float* b2 = (const float*)d_in[5];
    const int* src = ei;
    const int* dst = ei + Ee;

    float* dinv  = (float*)d_ws;                    // N
    float* xd8   = dinv + Nn;                       // N*8
    float* h2d   = xd8 + (size_t)Nn * 8;            // N
    float* degp  = h2d + Nn;                        // 12*N region (deg uses 8, outp uses 12)
    float* pre1p = degp + (size_t)CPB2 * Nn;        // CPB2*N5 (24 MB)
    unsigned int* recs = (unsigned int*)(pre1p + (size_t)CPB2 * N5);  // NB2*BCAP (7.2 MB)
    int* bcnt = (int*)(recs + (size_t)NB2 * BCAP);  // NB2 ints
    float* outp = degp;                             // alias: deg consumed before layer 2
    float* out  = (float*)d_out;

    hipMemsetAsync(bcnt, 0, NB2 * sizeof(int), stream);

    partition_kernel<<<PBLK, 512, 0, stream>>>(src, dst, recs, bcnt);
    degbin2_kernel<<<NB2 * CPB1, 512, 0, stream>>>(recs, bcnt, degp);
    prep_kernel<<<(Nn + 255) / 256, 256, 0, stream>>>(x, degp, dinv, xd8);
    pre1bin3_kernel<<<NB2 * CPB2, TPB, 0, stream>>>(recs, bcnt, xd8, pre1p);
    node1_kernel<<<(Nn + 255) / 256, 256, 0, stream>>>(pre1p, xd8, W1, b1, W2, dinv, h2d);
    out2bin3_kernel<<<NB2 * CPB2, TPB, 0, stream>>>(recs, bcnt, h2d, outp);
    final_kernel<<<(Nn + 255) / 256, 256, 0, stream>>>(outp, h2d, dinv, b2, out);
}

// Round 9
// 118.886 us; speedup vs baseline: 1.0797x; 1.0797x over previous
//
#include <hip/hip_runtime.h>
#include <hip/hip_fp16.h>

#define Nn 100000
#define Ee 1600000
#define HID 128
#define IN_DIM 5
#define N5 (Nn * IN_DIM)

// ---- bucket geometry: 1024 nodes/bucket, 98 buckets ----
#define SH2 10
#define BSZ2 1024
#define NB2 98
#define BCAP 18432        // expect ~16327, sigma ~128

#define PCHUNK 2000       // edges per partition block
#define PBLK (Ee / PCHUNK)   // 800 blocks

#define CPB2 12           // chunks/bucket for gather passes -> grid 1176

union F2H { float f; __half2 h; };

// ---------- kernel 1: one-pass radix partition of the edge list ----------
// rec = (d_local << 17) | src   (src < 2^17, d_local < 2^10)
__global__ __launch_bounds__(512) void partition_kernel(const int* __restrict__ src,
                                                        const int* __restrict__ dst,
                                                        unsigned int* __restrict__ recs,
                                                        int* __restrict__ bcnt) {
    __shared__ unsigned int stage[PCHUNK];   // 8 KB
    __shared__ int hist[NB2 + 1];
    __shared__ int cur[NB2];
    __shared__ int gbase[NB2];
    int e0 = blockIdx.x * PCHUNK;
    if (threadIdx.x <= NB2) hist[threadIdx.x] = 0;
    __syncthreads();
    for (int e = e0 + threadIdx.x; e < e0 + PCHUNK; e += 512)
        atomicAdd(&hist[(dst[e] >> SH2) + 1], 1);
    __syncthreads();
    if (threadIdx.x == 0)
        for (int b = 1; b <= NB2; ++b) hist[b] += hist[b - 1];
    __syncthreads();
    if (threadIdx.x < NB2) {
        int c0 = hist[threadIdx.x], c1 = hist[threadIdx.x + 1];
        cur[threadIdx.x] = c0;
        gbase[threadIdx.x] = atomicAdd(&bcnt[threadIdx.x], c1 - c0);
    }
    __syncthreads();
    for (int e = e0 + threadIdx.x; e < e0 + PCHUNK; e += 512) {
        int d = dst[e], s = src[e];
        int b = d >> SH2;
        int slot = atomicAdd(&cur[b], 1);
        stage[slot] = ((unsigned int)(d & (BSZ2 - 1)) << 17) | (unsigned int)s;
    }
    __syncthreads();
    int wave = threadIdx.x >> 6, lane = threadIdx.x & 63;
    for (int b = wave; b < NB2; b += 8) {
        int c0 = hist[b], len = hist[b + 1] - c0;
        unsigned int* o = recs + (size_t)b * BCAP + gbase[b];
        for (int i = lane; i < len; i += 64) o[i] = stage[c0 + i];
    }
}

// ---------- kernel 2: in-degree, one block per bucket (exclusive, no partials) ----------
__global__ __launch_bounds__(1024) void degbin_kernel(const unsigned int* __restrict__ recs,
                                                      const int* __restrict__ bcnt,
                                                      float* __restrict__ deg) {
    __shared__ int acc[BSZ2];                // 4 KB
    int b = blockIdx.x;
    int n = bcnt[b];
    acc[threadIdx.x] = 0;
    __syncthreads();
    const unsigned int* R = recs + (size_t)b * BCAP;
    int i = (int)threadIdx.x;
    for (; i + 3072 < n; i += 4096) {
        unsigned int ra = R[i], rb = R[i + 1024], rc = R[i + 2048], rd = R[i + 3072];
        atomicAdd(&acc[ra >> 17], 1);
        atomicAdd(&acc[rb >> 17], 1);
        atomicAdd(&acc[rc >> 17], 1);
        atomicAdd(&acc[rd >> 17], 1);
    }
    for (; i < n; i += 1024) atomicAdd(&acc[R[i] >> 17], 1);
    __syncthreads();
    int g = (b << SH2) + threadIdx.x;
    if (g < Nn) deg[g] = (float)acc[threadIdx.x];
}

// ---------- kernel 3: dinv = rsqrt(deg+1); xd16 = packed [f32 x3 | f16 x2] * dinv ----------
__global__ void prep_kernel(const float* __restrict__ x, float* __restrict__ deg_dinv,
                            float4* __restrict__ xd16) {
    int i = blockIdx.x * blockDim.x + threadIdx.x;
    if (i < Nn) {
        float di = rsqrtf(deg_dinv[i] + 1.0f);
        deg_dinv[i] = di;
        float4 o;
        o.x = x[i * IN_DIM + 0] * di;
        o.y = x[i * IN_DIM + 1] * di;
        o.z = x[i * IN_DIM + 2] * di;
        F2H u;
        u.h = __floats2half2_rn(x[i * IN_DIM + 3] * di, x[i * IN_DIM + 4] * di);
        o.w = u.f;
        xd16[i] = o;
    }
}

// ---------- kernel 4: layer-1 input aggregation (single 16B gather per record) ----------
__global__ __launch_bounds__(512) void pre1bin_kernel(const unsigned int* __restrict__ recs,
                                                      const int* __restrict__ bcnt,
                                                      const float4* __restrict__ xd16,
                                                      float* __restrict__ pre1p) {
    __shared__ float acc[BSZ2 * IN_DIM];     // 20 KB
    int b = blockIdx.x / CPB2, c = blockIdx.x % CPB2;
    int n = bcnt[b];
    int r0 = (int)((long long)n * c / CPB2), r1 = (int)((long long)n * (c + 1) / CPB2);
    float4* accv = (float4*)acc;
    for (int i = threadIdx.x; i < BSZ2 * IN_DIM / 4; i += 512)
        accv[i] = make_float4(0.f, 0.f, 0.f, 0.f);
    __syncthreads();
    const unsigned int* R = recs + (size_t)b * BCAP;
    int i = r0 + (int)threadIdx.x;
    for (; i + 512 < r1; i += 1024) {
        unsigned int ra = R[i], rb = R[i + 512];
        float4 va = xd16[ra & 0x1FFFFu];
        float4 vb = xd16[rb & 0x1FFFFu];
        F2H ua; ua.f = va.w; float2 ea = __half22float2(ua.h);
        F2H ub; ub.f = vb.w; float2 eb = __half22float2(ub.h);
        int da = (int)(ra >> 17) * IN_DIM, db = (int)(rb >> 17) * IN_DIM;
        atomicAdd(&acc[da + 0], va.x);
        atomicAdd(&acc[da + 1], va.y);
        atomicAdd(&acc[da + 2], va.z);
        atomicAdd(&acc[da + 3], ea.x);
        atomicAdd(&acc[da + 4], ea.y);
        atomicAdd(&acc[db + 0], vb.x);
        atomicAdd(&acc[db + 1], vb.y);
        atomicAdd(&acc[db + 2], vb.z);
        atomicAdd(&acc[db + 3], eb.x);
        atomicAdd(&acc[db + 4], eb.y);
    }
    if (i < r1) {
        unsigned int ra = R[i];
        float4 va = xd16[ra & 0x1FFFFu];
        F2H ua; ua.f = va.w; float2 ea = __half22float2(ua.h);
        int da = (int)(ra >> 17) * IN_DIM;
        atomicAdd(&acc[da + 0], va.x);
        atomicAdd(&acc[da + 1], va.y);
        atomicAdd(&acc[da + 2], va.z);
        atomicAdd(&acc[da + 3], ea.x);
        atomicAdd(&acc[da + 4], ea.y);
    }
    __syncthreads();
    int base = b << SH2;
    int cnt4 = min(BSZ2, Nn - base) * IN_DIM / 4;
    float4* o = (float4*)(pre1p + (size_t)c * N5 + (size_t)base * IN_DIM);
    for (int j = threadIdx.x; j < cnt4; j += 512) o[j] = accv[j];
}

// ---------- kernel 5: fused partial-reduce + layer-1 finish + ReLU + layer-2 proj ----------
__global__ __launch_bounds__(256) void node1_kernel(const float* __restrict__ pre1p,
                             const float4* __restrict__ xd16,
                             const float* __restrict__ W1, const float* __restrict__ b1,
                             const float* __restrict__ W2, const float* __restrict__ dinv,
                             float* __restrict__ h2d) {
    __shared__ float w1s[IN_DIM * HID];      // 2.5 KB
    __shared__ float w2s[HID], b1s[HID];
    int tid = threadIdx.x;
    for (int j = tid; j < IN_DIM * HID; j += 256) w1s[j] = W1[j];
    if (tid < HID) { w2s[tid] = W2[tid]; b1s[tid] = b1[tid]; }
    __syncthreads();
    int nnode = blockIdx.x * 256 + tid;
    if (nnode >= Nn) return;
    float a5[IN_DIM] = {0.f, 0.f, 0.f, 0.f, 0.f};
    #pragma unroll
    for (int c = 0; c < CPB2; ++c) {
        const float* p = pre1p + (size_t)c * N5 + (size_t)nnode * IN_DIM;
        #pragma unroll
        for (int k = 0; k < IN_DIM; ++k) a5[k] += p[k];
    }
    float4 s = xd16[nnode];
    F2H u; u.f = s.w; float2 se = __half22float2(u.h);
    float di = dinv[nnode];
    a5[0] = (a5[0] + s.x) * di;
    a5[1] = (a5[1] + s.y) * di;
    a5[2] = (a5[2] + s.z) * di;
    a5[3] = (a5[3] + se.x) * di;
    a5[4] = (a5[4] + se.y) * di;
    float accp = 0.f;
    #pragma unroll
    for (int f = 0; f < HID; ++f) {
        float v = b1s[f];
        #pragma unroll
        for (int k = 0; k < IN_DIM; ++k) v += a5[k] * w1s[k * HID + f];
        v = fmaxf(v, 0.f);
        accp += v * w2s[f];
    }
    h2d[nnode] = accp * di;
}

// ---------- kernel 6: layer-2 scalar aggregation ----------
__global__ __launch_bounds__(512) void out2bin_kernel(const unsigned int* __restrict__ recs,
                                                      const int* __restrict__ bcnt,
                                                      const float* __restrict__ h2d,
                                                      float* __restrict__ outp) {
    __shared__ float acc[BSZ2];              // 4 KB
    int b = blockIdx.x / CPB2, c = blockIdx.x % CPB2;
    int n = bcnt[b];
    int r0 = (int)((long long)n * c / CPB2), r1 = (int)((long long)n * (c + 1) / CPB2);
    for (int i = threadIdx.x; i < BSZ2; i += 512) acc[i] = 0.f;
    __syncthreads();
    const unsigned int* R = recs + (size_t)b * BCAP;
    int i = r0 + (int)threadIdx.x;
    for (; i + 512 < r1; i += 1024) {
        unsigned int ra = R[i], rb = R[i + 512];
        float ha = h2d[ra & 0x1FFFFu];
        float hb = h2d[rb & 0x1FFFFu];
        atomicAdd(&acc[ra >> 17], ha);
        atomicAdd(&acc[rb >> 17], hb);
    }
    if (i < r1) {
        unsigned int ra = R[i];
        atomicAdd(&acc[ra >> 17], h2d[ra & 0x1FFFFu]);
    }
    __syncthreads();
    int base = b << SH2;
    int cnt = min(BSZ2, Nn - base);
    float* o = outp + (size_t)c * Nn + base;
    for (int j = threadIdx.x; j < cnt; j += 512) o[j] = acc[j];
}

// ---------- kernel 7: final reduce + self-loop + b2 ----------
__global__ void final_kernel(const float* __restrict__ outp, const float* __restrict__ h2d,
                             const float* __restrict__ dinv, const float* __restrict__ b2,
                             float* __restrict__ out) {
    int n = blockIdx.x * blockDim.x + threadIdx.x;
    if (n < Nn) {
        float v = 0.f;
        #pragma unroll
        for (int c = 0; c < CPB2; ++c) v += outp[(size_t)c * Nn + n];
        out[n] = (v + h2d[n]) * dinv[n] + b2[0];
    }
}

extern "C" void kernel_launch(void* const* d_in, const int* in_sizes, int n_in,
                              void* d_out, int out_size, void* d_ws, size_t ws_size,
                              hipStream_t stream) {
    const float* x  = (const float*)d_in[0];
    const int*   ei = (const int*)d_in[1];     // [2, E]: src row then dst row
    const float* W1 = (const float*)d_in[2];
    const float* b1 = (const float*)d_in[3];
    const float* W2 = (const float*)d_in[4];
    const float* b2 = (const float*)d_in[5];
    const int* src = ei;
    const int* dst = ei + Ee;

    float* dinv  = (float*)d_ws;                    // N (deg -> dinv in place)
    float4* xd16 = (float4*)(dinv + Nn);            // N float4s (1.6 MB)
    float* h2d   = (float*)(xd16 + Nn);             // N
    float* outp  = h2d + Nn;                        // CPB2*N (4.8 MB)
    float* pre1p = outp + (size_t)CPB2 * Nn;        // CPB2*N5 (24 MB)
    unsigned int* recs = (unsigned int*)(pre1p + (size_t)CPB2 * N5);  // NB2*BCAP (7.2 MB)
    int* bcnt = (int*)(recs + (size_t)NB2 * BCAP);  // NB2 ints
    float* out  = (float*)d_out;

    hipMemsetAsync(bcnt, 0, NB2 * sizeof(int), stream);

    partition_kernel<<<PBLK, 512, 0, stream>>>(src, dst, recs, bcnt);
    degbin_kernel<<<NB2, 1024, 0, stream>>>(recs, bcnt, dinv);
    prep_kernel<<<(Nn + 255) / 256, 256, 0, stream>>>(x, dinv, xd16);
    pre1bin_kernel<<<NB2 * CPB2, 512, 0, stream>>>(recs, bcnt, xd16, pre1p);
    node1_kernel<<<(Nn + 255) / 256, 256, 0, stream>>>(pre1p, xd16, W1, b1, W2, dinv, h2d);
    out2bin_kernel<<<NB2 * CPB2, 512, 0, stream>>>(recs, bcnt, h2d, outp);
    final_kernel<<<(Nn + 255) / 256, 256, 0, stream>>>(outp, h2d, dinv, b2, out);
}

// Round 11
// 117.948 us; speedup vs baseline: 1.0882x; 1.0080x over previous
//
#include <hip/hip_runtime.h>
#include <hip/hip_fp16.h>

#define Nn 100000
#define Ee 1600000
#define HID 128
#define IN_DIM 5
#define N5 (Nn * IN_DIM)

// ---- bucket geometry: 1024 nodes/bucket, 98 buckets ----
#define SH2 10
#define BSZ2 1024
#define NB2 98
#define BCAP 18432        // expect ~16327, sigma ~128

#define PCHUNK 4000       // edges per partition block
#define PBLK (Ee / PCHUNK)   // 400 blocks

#define CPB 6             // chunks/bucket for gather passes -> grid 588

typedef float f32x4 __attribute__((ext_vector_type(4)));
union F2H { float f; __half2 h; };

// ---- sc0 (bypass CU cache) gathers, dual-issue in one asm block for MLP ----
__device__ __forceinline__ void gather2_sc0_16(const float4* pa, const float4* pb,
                                               f32x4& va, f32x4& vb) {
    asm volatile("global_load_dwordx4 %0, %2, off sc0\n\t"
                 "global_load_dwordx4 %1, %3, off sc0\n\t"
                 "s_waitcnt vmcnt(0)"
                 : "=v"(va), "=v"(vb) : "v"(pa), "v"(pb) : "memory");
}
__device__ __forceinline__ f32x4 gather1_sc0_16(const float4* p) {
    f32x4 v;
    asm volatile("global_load_dwordx4 %0, %1, off sc0\n\t"
                 "s_waitcnt vmcnt(0)"
                 : "=v"(v) : "v"(p) : "memory");
    return v;
}
__device__ __forceinline__ void gather2_sc0_4(const float* pa, const float* pb,
                                              float& va, float& vb) {
    asm volatile("global_load_dword %0, %2, off sc0\n\t"
                 "global_load_dword %1, %3, off sc0\n\t"
                 "s_waitcnt vmcnt(0)"
                 : "=v"(va), "=v"(vb) : "v"(pa), "v"(pb) : "memory");
}
__device__ __forceinline__ float gather1_sc0_4(const float* p) {
    float v;
    asm volatile("global_load_dword %0, %1, off sc0\n\t"
                 "s_waitcnt vmcnt(0)"
                 : "=v"(v) : "v"(p) : "memory");
    return v;
}

// ---------- kernel 1: one-pass radix partition of the edge list ----------
// rec = (d_local << 17) | src   (src < 2^17, d_local < 2^10)
__global__ __launch_bounds__(512) void partition_kernel(const int* __restrict__ src,
                                                        const int* __restrict__ dst,
                                                        unsigned int* __restrict__ recs,
                                                        int* __restrict__ bcnt) {
    __shared__ unsigned int stage[PCHUNK];   // 16 KB
    __shared__ int hist[NB2 + 1];
    __shared__ int cur[NB2];
    __shared__ int gbase[NB2];
    int e0 = blockIdx.x * PCHUNK;
    if (threadIdx.x <= NB2) hist[threadIdx.x] = 0;
    __syncthreads();
    for (int e = e0 + threadIdx.x; e < e0 + PCHUNK; e += 512)
        atomicAdd(&hist[(dst[e] >> SH2) + 1], 1);
    __syncthreads();
    if (threadIdx.x == 0)
        for (int b = 1; b <= NB2; ++b) hist[b] += hist[b - 1];
    __syncthreads();
    if (threadIdx.x < NB2) {
        int c0 = hist[threadIdx.x], c1 = hist[threadIdx.x + 1];
        cur[threadIdx.x] = c0;
        gbase[threadIdx.x] = atomicAdd(&bcnt[threadIdx.x], c1 - c0);
    }
    __syncthreads();
    for (int e = e0 + threadIdx.x; e < e0 + PCHUNK; e += 512) {
        int d = dst[e], s = src[e];
        int b = d >> SH2;
        int slot = atomicAdd(&cur[b], 1);
        stage[slot] = ((unsigned int)(d & (BSZ2 - 1)) << 17) | (unsigned int)s;
    }
    __syncthreads();
    int wave = threadIdx.x >> 6, lane = threadIdx.x & 63;
    for (int b = wave; b < NB2; b += 8) {
        int c0 = hist[b], len = hist[b + 1] - c0;
        unsigned int* o = recs + (size_t)b * BCAP + gbase[b];
        for (int i = lane; i < len; i += 64) o[i] = stage[c0 + i];
    }
}

// ---------- kernel 2: in-degree, one block per bucket ----------
__global__ __launch_bounds__(1024) void degbin_kernel(const unsigned int* __restrict__ recs,
                                                      const int* __restrict__ bcnt,
                                                      float* __restrict__ deg) {
    __shared__ int acc[BSZ2];                // 4 KB
    int b = blockIdx.x;
    int n = bcnt[b];
    acc[threadIdx.x] = 0;
    __syncthreads();
    const unsigned int* R = recs + (size_t)b * BCAP;
    int i = (int)threadIdx.x;
    for (; i + 3072 < n; i += 4096) {
        unsigned int ra = R[i], rb = R[i + 1024], rc = R[i + 2048], rd = R[i + 3072];
        atomicAdd(&acc[ra >> 17], 1);
        atomicAdd(&acc[rb >> 17], 1);
        atomicAdd(&acc[rc >> 17], 1);
        atomicAdd(&acc[rd >> 17], 1);
    }
    for (; i < n; i += 1024) atomicAdd(&acc[R[i] >> 17], 1);
    __syncthreads();
    int g = (b << SH2) + threadIdx.x;
    if (g < Nn) deg[g] = (float)acc[threadIdx.x];
}

// ---------- kernel 3: dinv = rsqrt(deg+1); xd16 = packed [f32 x3 | f16 x2] * dinv ----------
__global__ void prep_kernel(const float* __restrict__ x, float* __restrict__ deg_dinv,
                            float4* __restrict__ xd16) {
    int i = blockIdx.x * blockDim.x + threadIdx.x;
    if (i < Nn) {
        float di = rsqrtf(deg_dinv[i] + 1.0f);
        deg_dinv[i] = di;
        float4 o;
        o.x = x[i * IN_DIM + 0] * di;
        o.y = x[i * IN_DIM + 1] * di;
        o.z = x[i * IN_DIM + 2] * di;
        F2H u;
        u.h = __floats2half2_rn(x[i * IN_DIM + 3] * di, x[i * IN_DIM + 4] * di);
        o.w = u.f;
        xd16[i] = o;
    }
}

// ---------- kernel 4: layer-1 input aggregation (sc0 gathers) ----------
__global__ __launch_bounds__(512) void pre1bin_kernel(const unsigned int* __restrict__ recs,
                                                      const int* __restrict__ bcnt,
                                                      const float4* __restrict__ xd16,
                                                      float* __restrict__ pre1p) {
    __shared__ float acc[BSZ2 * IN_DIM];     // 20 KB
    int b = blockIdx.x / CPB, c = blockIdx.x % CPB;
    int n = bcnt[b];
    int r0 = (int)((long long)n * c / CPB), r1 = (int)((long long)n * (c + 1) / CPB);
    f32x4* accv = (f32x4*)acc;
    for (int i = threadIdx.x; i < BSZ2 * IN_DIM / 4; i += 512)
        accv[i] = (f32x4)(0.f);
    __syncthreads();
    const unsigned int* R = recs + (size_t)b * BCAP;
    int i = r0 + (int)threadIdx.x;
    for (; i + 512 < r1; i += 1024) {
        unsigned int ra = R[i], rb = R[i + 512];
        f32x4 va, vb;
        gather2_sc0_16(&xd16[ra & 0x1FFFFu], &xd16[rb & 0x1FFFFu], va, vb);
        F2H ua; ua.f = va.w; float2 ea = __half22float2(ua.h);
        F2H ub; ub.f = vb.w; float2 eb = __half22float2(ub.h);
        int da = (int)(ra >> 17) * IN_DIM, db = (int)(rb >> 17) * IN_DIM;
        atomicAdd(&acc[da + 0], va.x);
        atomicAdd(&acc[da + 1], va.y);
        atomicAdd(&acc[da + 2], va.z);
        atomicAdd(&acc[da + 3], ea.x);
        atomicAdd(&acc[da + 4], ea.y);
        atomicAdd(&acc[db + 0], vb.x);
        atomicAdd(&acc[db + 1], vb.y);
        atomicAdd(&acc[db + 2], vb.z);
        atomicAdd(&acc[db + 3], eb.x);
        atomicAdd(&acc[db + 4], eb.y);
    }
    if (i < r1) {
        unsigned int ra = R[i];
        f32x4 va = gather1_sc0_16(&xd16[ra & 0x1FFFFu]);
        F2H ua; ua.f = va.w; float2 ea = __half22float2(ua.h);
        int da = (int)(ra >> 17) * IN_DIM;
        atomicAdd(&acc[da + 0], va.x);
        atomicAdd(&acc[da + 1], va.y);
        atomicAdd(&acc[da + 2], va.z);
        atomicAdd(&acc[da + 3], ea.x);
        atomicAdd(&acc[da + 4], ea.y);
    }
    __syncthreads();
    int base = b << SH2;
    int cnt4 = min(BSZ2, Nn - base) * IN_DIM / 4;
    f32x4* o = (f32x4*)(pre1p + (size_t)c * N5 + (size_t)base * IN_DIM);
    for (int j = threadIdx.x; j < cnt4; j += 512)
        __builtin_nontemporal_store(accv[j], &o[j]);
}

// ---------- kernel 5: fused partial-reduce + layer-1 finish + ReLU + layer-2 proj ----------
__global__ __launch_bounds__(256) void node1_kernel(const float* __restrict__ pre1p,
                             const float4* __restrict__ xd16,
                             const float* __restrict__ W1, const float* __restrict__ b1,
                             const float* __restrict__ W2, const float* __restrict__ dinv,
                             float* __restrict__ h2d) {
    __shared__ float w1s[IN_DIM * HID];      // 2.5 KB
    __shared__ float w2s[HID], b1s[HID];
    int tid = threadIdx.x;
    for (int j = tid; j < IN_DIM * HID; j += 256) w1s[j] = W1[j];
    if (tid < HID) { w2s[tid] = W2[tid]; b1s[tid] = b1[tid]; }
    __syncthreads();
    int nnode = blockIdx.x * 256 + tid;
    if (nnode >= Nn) return;
    float a5[IN_DIM] = {0.f, 0.f, 0.f, 0.f, 0.f};
    #pragma unroll
    for (int c = 0; c < CPB; ++c) {
        const float* p = pre1p + (size_t)c * N5 + (size_t)nnode * IN_DIM;
        #pragma unroll
        for (int k = 0; k < IN_DIM; ++k) a5[k] += p[k];
    }
    float4 s = xd16[nnode];
    F2H u; u.f = s.w; float2 se = __half22float2(u.h);
    float di = dinv[nnode];
    a5[0] = (a5[0] + s.x) * di;
    a5[1] = (a5[1] + s.y) * di;
    a5[2] = (a5[2] + s.z) * di;
    a5[3] = (a5[3] + se.x) * di;
    a5[4] = (a5[4] + se.y) * di;
    float accp = 0.f;
    #pragma unroll
    for (int f = 0; f < HID; ++f) {
        float v = b1s[f];
        #pragma unroll
        for (int k = 0; k < IN_DIM; ++k) v += a5[k] * w1s[k * HID + f];
        v = fmaxf(v, 0.f);
        accp += v * w2s[f];
    }
    h2d[nnode] = accp * di;
}

// ---------- kernel 6: layer-2 scalar aggregation (sc0 gathers) ----------
__global__ __launch_bounds__(512) void out2bin_kernel(const unsigned int* __restrict__ recs,
                                                      const int* __restrict__ bcnt,
                                                      const float* __restrict__ h2d,
                                                      float* __restrict__ outp) {
    __shared__ float acc[BSZ2];              // 4 KB
    int b = blockIdx.x / CPB, c = blockIdx.x % CPB;
    int n = bcnt[b];
    int r0 = (int)((long long)n * c / CPB), r1 = (int)((long long)n * (c + 1) / CPB);
    for (int i = threadIdx.x; i < BSZ2; i += 512) acc[i] = 0.f;
    __syncthreads();
    const unsigned int* R = recs + (size_t)b * BCAP;
    int i = r0 + (int)threadIdx.x;
    for (; i + 512 < r1; i += 1024) {
        unsigned int ra = __builtin_nontemporal_load(&R[i]);
        unsigned int rb = __builtin_nontemporal_load(&R[i + 512]);
        float ha, hb;
        gather2_sc0_4(&h2d[ra & 0x1FFFFu], &h2d[rb & 0x1FFFFu], ha, hb);
        atomicAdd(&acc[ra >> 17], ha);
        atomicAdd(&acc[rb >> 17], hb);
    }
    if (i < r1) {
        unsigned int ra = __builtin_nontemporal_load(&R[i]);
        float ha = gather1_sc0_4(&h2d[ra & 0x1FFFFu]);
        atomicAdd(&acc[ra >> 17], ha);
    }
    __syncthreads();
    int base = b << SH2;
    int cnt = min(BSZ2, Nn - base);
    float* o = outp + (size_t)c * Nn + base;
    for (int j = threadIdx.x; j < cnt; j += 512)
        __builtin_nontemporal_store(acc[j], &o[j]);
}

// ---------- kernel 7: final reduce + self-loop + b2 ----------
__global__ void final_kernel(const float* __restrict__ outp, const float* __restrict__ h2d,
                             const float* __restrict__ dinv, const float* __restrict__ b2,
                             float* __restrict__ out) {
    int n = blockIdx.x * blockDim.x + threadIdx.x;
    if (n < Nn) {
        float v = 0.f;
        #pragma unroll
        for (int c = 0; c < CPB; ++c) v += outp[(size_t)c * Nn + n];
        out[n] = (v + h2d[n]) * dinv[n] + b2[0];
    }
}

extern "C" void kernel_launch(void* const* d_in, const int* in_sizes, int n_in,
                              void* d_out, int out_size, void* d_ws, size_t ws_size,
                              hipStream_t stream) {
    const float* x  = (const float*)d_in[0];
    const int*   ei = (const int*)d_in[1];     // [2, E]: src row then dst row
    const float* W1 = (const float*)d_in[2];
    const float* b1 = (const float*)d_in[3];
    const float* W2 = (const float*)d_in[4];
    const float* b2 = (const float*)d_in[5];
    const int* src = ei;
    const int* dst = ei + Ee;

    float* dinv  = (float*)d_ws;                    // N (deg -> dinv in place)
    float4* xd16 = (float4*)(dinv + Nn);            // N float4s (1.6 MB)
    float* h2d   = (float*)(xd16 + Nn);             // N
    float* outp  = h2d + Nn;                        // CPB*N (2.4 MB)
    float* pre1p = outp + (size_t)CPB * Nn;         // CPB*N5 (12 MB)
    unsigned int* recs = (unsigned int*)(pre1p + (size_t)CPB * N5);  // NB2*BCAP (7.2 MB)
    int* bcnt = (int*)(recs + (size_t)NB2 * BCAP);  // NB2 ints
    float* out  = (float*)d_out;

    (void)hipMemsetAsync(bcnt, 0, NB2 * sizeof(int), stream);

    partition_kernel<<<PBLK, 512, 0, stream>>>(src, dst, recs, bcnt);
    degbin_kernel<<<NB2, 1024, 0, stream>>>(recs, bcnt, dinv);
    prep_kernel<<<(Nn + 255) / 256, 256, 0, stream>>>(x, dinv, xd16);
    pre1bin_kernel<<<NB2 * CPB, 512, 0, stream>>>(recs, bcnt, xd16, pre1p);
    node1_kernel<<<(Nn + 255) / 256, 256, 0, stream>>>(pre1p, xd16, W1, b1, W2, dinv, h2d);
    out2bin_kernel<<<NB2 * CPB, 512, 0, stream>>>(recs, bcnt, h2d, outp);
    final_kernel<<<(Nn + 255) / 256, 256, 0, stream>>>(outp, h2d, dinv, b2, out);
}